// Round 17
// baseline (2111.018 us; speedup 1.0000x reference)
//
#include <hip/hip_runtime.h>
#include <hip/hip_bf16.h>

// Shapes fixed: B=8, L=S=1024, D=1024, H=16, E=64, TOP_K=8.
// d_out = [ out (B*L*D f32) | A (B*H*L*S f32) ]
//
// Reference model (R16): np reference = numpy linked against AMD AOCL/BLIS
// (EPYC pod):
//  - projections: BLIS sgemm, fixed KC=512 loop -> K=1024 panels {512,512}
//    (flush at k=512, 1024). Per element: ascending-k f32 FMA chain within
//    a panel (BLIS 6x16 zen ukernel: serial vfmadd per element); panels
//    combined into C by single f32 adds; then +bias, relu.
//  - scores: einsum evaluated as batched matmul (BLAS, K=64 < KC -> single
//    panel): ONE ascending-e f32 FMA chain per score. [Established: with
//    proj fixed, chain-einsum captures dominant row X where c_einsum
//    SSE3/AVX512 models never do (R9 vs R8a, R7 vs R3).]
// Selection: thresh = 8th largest (multiplicity-counted); kept = s >= thresh.
// Value-level paths (softmax values, A*v, out gemm) are bf16-forgiving f32.

#define B_ 8
#define L_ 1024
#define S_ 1024
#define D_ 1024
#define H_ 16
#define E_ 64
#define TOPK_ 8

// ---------------------------------------------------------------------------
// C = A(MxK,row) * B(NxK,row)^T + bias, optional relu. f32; ascending-k FMA
// chain within BLIS panels {512,512} (flush after k-tiles 31, 63 for
// K=1024), f32 adds across panels.
// ---------------------------------------------------------------------------
template <int RELU>
__global__ __launch_bounds__(256) void gemm_abt(
    const float* __restrict__ A, const float* __restrict__ Bm,
    const float* __restrict__ bias, float* __restrict__ C,
    int M, int N, int K, int lda, int ldb, int ldc) {
  __shared__ float As[16][68];
  __shared__ float Bs[16][68];

  const int t = threadIdx.x;
  const int tx = t & 15, ty = t >> 4;
  const int m0 = blockIdx.y * 64, n0 = blockIdx.x * 64;

  float acc[4][4], tot[4][4];
#pragma unroll
  for (int r = 0; r < 4; ++r)
#pragma unroll
    for (int c = 0; c < 4; ++c) {
      acc[r][c] = 0.0f;
      tot[r][c] = 0.0f;
    }

  const int ntiles = K / 16;
  for (int ti = 0; ti < ntiles; ++ti) {
    const int kt = ti * 16;
    __syncthreads();
#pragma unroll
    for (int i = 0; i < 4; ++i) {
      const int idx = t + 256 * i;
      const int r = idx >> 4, kk = idx & 15;
      As[kk][r] = A[(long long)(m0 + r) * lda + kt + kk];
      Bs[kk][r] = Bm[(long long)(n0 + r) * ldb + kt + kk];
    }
    __syncthreads();
#pragma unroll
    for (int kk = 0; kk < 16; ++kk) {
      const float4 a4 = *reinterpret_cast<const float4*>(&As[kk][ty * 4]);
      const float4 b4 = *reinterpret_cast<const float4*>(&Bs[kk][tx * 4]);
      const float av[4] = {a4.x, a4.y, a4.z, a4.w};
      const float bv[4] = {b4.x, b4.y, b4.z, b4.w};
#pragma unroll
      for (int r = 0; r < 4; ++r)
#pragma unroll
        for (int c = 0; c < 4; ++c) acc[r][c] = fmaf(av[r], bv[c], acc[r][c]);
    }
    // BLIS fixed KC=512: flush after k-tile 31 (k=512) and 63 (k=1024).
    const bool flush =
        (K == 1024) ? (ti == 31 || ti == 63) : (ti == ntiles - 1);
    if (flush) {
#pragma unroll
      for (int r = 0; r < 4; ++r)
#pragma unroll
        for (int c = 0; c < 4; ++c) {
          tot[r][c] = __fadd_rn(tot[r][c], acc[r][c]);
          acc[r][c] = 0.0f;
        }
    }
  }

#pragma unroll
  for (int r = 0; r < 4; ++r) {
    const int m = m0 + ty * 4 + r;
#pragma unroll
    for (int c = 0; c < 4; ++c) {
      const int n = n0 + tx * 4 + c;
      float v = tot[r][c];
      if (bias) v = __fadd_rn(v, bias[n]);
      if (RELU) v = fmaxf(v, 0.0f);
      C[(long long)m * ldc + n] = v;
    }
  }
}

// ---------------------------------------------------------------------------
// Fused scores + top-8 threshold + masked softmax.
// Score dot: single ascending-e f32 FMA chain (BLAS K=64, single panel).
// Writes A (full row) and compact (idx,w) lists for the sparse A*v step.
// Block = 512 threads = 8 waves = 8 consecutive rows (same b,h).
// ---------------------------------------------------------------------------
__global__ __launch_bounds__(512) void score_topk_kernel(
    const float* __restrict__ Qf, const float* __restrict__ Kf,
    float* __restrict__ A, int* __restrict__ outIdx, float* __restrict__ outW,
    int* __restrict__ outCnt) {
#pragma clang fp contract(off)
  __shared__ float Ks[64][132];  // [e][s-local]
  __shared__ float qs[8][64];

  const int tid = threadIdx.x;
  const int wave = tid >> 6, lane = tid & 63;
  const long long row = (long long)blockIdx.x * 8 + wave;  // (b*16+h)*1024+l
  const int b = (int)(row >> 14);
  const int h = (int)((row >> 10) & 15);
  const int l = (int)(row & 1023);

  qs[wave][lane] = Qf[(((long long)(b << 10) + l) << 10) + (h << 6) + lane];
  const float* Kp = Kf + ((long long)(b << 10) << 10) + (h << 6);

  float s[16];
  for (int wt = 0; wt < 8; ++wt) {
    __syncthreads();
#pragma unroll
    for (int i = 0; i < 16; ++i) {
      const int idx = i * 512 + tid;
      const int sl = idx >> 6, e = idx & 63;
      Ks[e][sl] = Kp[((long long)(wt * 128 + sl) << 10) + e];
    }
    __syncthreads();

    const int c0 = 2 * lane, c1 = 2 * lane + 1;
    float a0 = 0.0f, a1 = 0.0f;
#pragma unroll
    for (int e = 0; e < 64; ++e) {
      const float qv = qs[wave][e];
      a0 = fmaf(qv, Ks[e][c0], a0);
      a1 = fmaf(qv, Ks[e][c1], a1);
    }
    s[2 * wt] = a0;
    s[2 * wt + 1] = a1;
  }

  // iterative top-8: find+remove max 8 times (multiplicity-correct; keeps
  // all ties at the final threshold)
  unsigned act = 0xFFFFu;
  float rowmax = 0.f, thresh = 0.f;
  for (int it = 0; it < TOPK_; ++it) {
    float lm = -INFINITY;
#pragma unroll
    for (int j = 0; j < 16; ++j)
      if (act & (1u << j)) lm = fmaxf(lm, s[j]);
    float m = lm;
#pragma unroll
    for (int d = 1; d < 64; d <<= 1) m = fmaxf(m, __shfl_xor(m, d));
    if (it == 0) rowmax = m;
    thresh = m;
    const bool has = (lm == m);
    const unsigned long long msk = __ballot(has);
    const int owner = __ffsll((long long)msk) - 1;
    if (lane == owner) {
      bool done = false;
#pragma unroll
      for (int j = 0; j < 16; ++j) {
        if (!done && (act & (1u << j)) && s[j] == m) {
          act &= ~(1u << j);
          done = true;
        }
      }
    }
  }

  float* a = A + row * (long long)S_;
  float e16[16];
  float zsum = 0.f;
#pragma unroll
  for (int j = 0; j < 16; ++j) {
    const bool kept = (s[j] >= thresh);
    e16[j] = kept ? expf((s[j] - rowmax) * 0.125f) : 0.0f;
    zsum += e16[j];
  }
#pragma unroll
  for (int d = 1; d < 64; d <<= 1) zsum += __shfl_xor(zsum, d);
  const float inv = 1.0f / zsum;

  int cnt = 0;
#pragma unroll
  for (int j = 0; j < 16; ++j) {
    const bool kept = (s[j] >= thresh);
    const float w = e16[j] * inv;
    const int sidx = (j >> 1) * 128 + 2 * lane + (j & 1);
    a[sidx] = kept ? w : 0.0f;
    const unsigned long long mk = __ballot(kept);
    if (kept) {
      const int pos = cnt + __popcll(mk & ((1ull << lane) - 1ull));
      if (pos < 16) {
        outIdx[row * 16 + pos] = sidx;
        outW[row * 16 + pos] = w;
      }
    }
    cnt += __popcll(mk);
  }
  if (lane == 0) outCnt[row] = cnt < 16 ? cnt : 16;
}

// ---------------------------------------------------------------------------
// Sparse A*v from compact lists. One wave per row (lane = e).
// ---------------------------------------------------------------------------
__global__ __launch_bounds__(256) void vagg_kernel(
    const int* __restrict__ idx, const float* __restrict__ w,
    const int* __restrict__ cnt, const float* __restrict__ Vp,
    float* __restrict__ Vagg) {
  const int wave = threadIdx.x >> 6;
  const int lane = threadIdx.x & 63;
  const long long row = (long long)blockIdx.x * 4 + wave;  // (b*16+h)*1024+l
  const int b = (int)(row >> 14);
  const int h = (int)((row >> 10) & 15);
  const int l = (int)(row & 1023);
  const int n = cnt[row];
  float acc = 0.0f;
  for (int i = 0; i < n; ++i) {
    const int sI = idx[row * 16 + i];
    const float ww = w[row * 16 + i];
    acc += ww * Vp[((long long)((b << 10) + sI) << 10) + (h << 6) + lane];
  }
  Vagg[((long long)((b << 10) + l) << 10) + (h << 6) + lane] = acc;
}

extern "C" void kernel_launch(void* const* d_in, const int* in_sizes, int n_in,
                              void* d_out, int out_size, void* d_ws,
                              size_t ws_size, hipStream_t stream) {
  const float* queries = (const float*)d_in[0];
  const float* keys = (const float*)d_in[1];
  const float* values = (const float*)d_in[2];
  const float* Wq = (const float*)d_in[3];
  const float* bq = (const float*)d_in[4];
  const float* Wk = (const float*)d_in[5];
  const float* bk = (const float*)d_in[6];
  const float* Wv = (const float*)d_in[7];
  const float* bv = (const float*)d_in[8];
  const float* Wo = (const float*)d_in[9];
  const float* bo = (const float*)d_in[10];

  float* out = (float*)d_out;                   // [B,L,D]
  float* Aout = out + (long long)B_ * L_ * D_;  // [B,H,L,S]

  char* ws = (char*)d_ws;
  const size_t MD = (size_t)B_ * L_ * D_ * sizeof(float);  // 33.55 MB
  const size_t NL = (size_t)B_ * H_ * L_;                   // 131072 rows
  float* Qf = (float*)ws;
  float* Kf = (float*)(ws + MD);
  int* tIdx = (int*)(ws + 2 * MD);
  float* tW = (float*)(ws + 2 * MD + NL * 16 * 4);
  int* tCnt = (int*)(ws + 2 * MD + NL * 16 * 8);
  float* Vb = (float*)(ws + 2 * MD + NL * 16 * 8 + NL * 4);
  float* Vagg = Qf;  // Qf dead after score kernel

  const dim3 blk(256);
  const int M = B_ * L_;  // 8192

  // Q = relu(queries @ Wq^T + bq)
  gemm_abt<1><<<dim3(16, M / 64), blk, 0, stream>>>(queries, Wq, bq, Qf, M, D_,
                                                    D_, D_, D_, D_);
  // K = keys @ Wk^T + bk
  gemm_abt<0><<<dim3(16, M / 64), blk, 0, stream>>>(keys, Wk, bk, Kf, M, D_,
                                                    D_, D_, D_, D_);
  // V = relu(values @ Wv^T + bv)
  gemm_abt<1><<<dim3(16, M / 64), blk, 0, stream>>>(values, Wv, bv, Vb, M, D_,
                                                    D_, D_, D_, D_);

  // fused scores + top-8 + softmax -> A + compact lists
  score_topk_kernel<<<(B_ * H_ * L_) / 8, dim3(512), 0, stream>>>(
      Qf, Kf, Aout, tIdx, tW, tCnt);

  // Vagg[b,l,h,:] = sum_s A * v   (writes into Qf slot)
  vagg_kernel<<<(B_ * H_ * L_) / 4, blk, 0, stream>>>(tIdx, tW, tCnt, Vb,
                                                      Vagg);

  // out = Vagg @ Wo^T + bo
  gemm_abt<0><<<dim3(16, M / 64), blk, 0, stream>>>(Vagg, Wo, bo, out, M, D_,
                                                    D_, D_, D_, D_);
}

// Round 18
// 1639.298 us; speedup vs baseline: 1.2878x; 1.2878x over previous
//
#include <hip/hip_runtime.h>
#include <hip/hip_bf16.h>

// Shapes: B=8, L=S=1024, D=1024, H=16, E=64, TOP_K=8.
// d_out = [ out (B*L*D f32) | A (B*H*L*S f32) ]
//
// PASSING reference model (R16, keep bit-exact):
//  - projections: ascending-k f32 FMA chain within K-panels {512,512}
//    (BLIS fixed KC=512), panels combined by single f32 adds; +bias, relu.
//  - scores: ONE ascending-e f32 FMA chain per score (K=64 single panel).
//  - top-8: thresh = 8th largest (multiplicity-counted); kept = s >= thresh.
// Value-level paths (softmax values, A*v, out gemm) are bf16-forgiving f32.
//
// R17 optimization: two-pass score path. Pass 1 computes bit-exact scores
// with q in registers (v_readlane broadcast) + conflict-free K tiles from a
// pre-transposed Kt; raw scores -> A region. Pass 2 does top8+softmax in
// place (HBM-bound). Replaces the 1180us fused kernel (60% VALU, 1e8 LDS
// bank conflicts).

#define B_ 8
#define L_ 1024
#define S_ 1024
#define D_ 1024
#define H_ 16
#define E_ 64
#define TOPK_ 8

// ---------------------------------------------------------------------------
// C = A(MxK,row) * B(NxK,row)^T + bias, optional relu. f32; ascending-k FMA
// chain within BLIS panels {512,512} (flush after k-tiles 31, 63), f32 adds
// across panels. (Bit-exact vs reference - do not reorder.)
// ---------------------------------------------------------------------------
template <int RELU>
__global__ __launch_bounds__(256) void gemm_abt(
    const float* __restrict__ A, const float* __restrict__ Bm,
    const float* __restrict__ bias, float* __restrict__ C,
    int M, int N, int K, int lda, int ldb, int ldc) {
  __shared__ float As[16][68];
  __shared__ float Bs[16][68];

  const int t = threadIdx.x;
  const int tx = t & 15, ty = t >> 4;
  const int m0 = blockIdx.y * 64, n0 = blockIdx.x * 64;

  float acc[4][4], tot[4][4];
#pragma unroll
  for (int r = 0; r < 4; ++r)
#pragma unroll
    for (int c = 0; c < 4; ++c) {
      acc[r][c] = 0.0f;
      tot[r][c] = 0.0f;
    }

  const int ntiles = K / 16;
  for (int ti = 0; ti < ntiles; ++ti) {
    const int kt = ti * 16;
    __syncthreads();
#pragma unroll
    for (int i = 0; i < 4; ++i) {
      const int idx = t + 256 * i;
      const int r = idx >> 4, kk = idx & 15;
      As[kk][r] = A[(long long)(m0 + r) * lda + kt + kk];
      Bs[kk][r] = Bm[(long long)(n0 + r) * ldb + kt + kk];
    }
    __syncthreads();
#pragma unroll
    for (int kk = 0; kk < 16; ++kk) {
      const float4 a4 = *reinterpret_cast<const float4*>(&As[kk][ty * 4]);
      const float4 b4 = *reinterpret_cast<const float4*>(&Bs[kk][tx * 4]);
      const float av[4] = {a4.x, a4.y, a4.z, a4.w};
      const float bv[4] = {b4.x, b4.y, b4.z, b4.w};
#pragma unroll
      for (int r = 0; r < 4; ++r)
#pragma unroll
        for (int c = 0; c < 4; ++c) acc[r][c] = fmaf(av[r], bv[c], acc[r][c]);
    }
    const bool flush =
        (K == 1024) ? (ti == 31 || ti == 63) : (ti == ntiles - 1);
    if (flush) {
#pragma unroll
      for (int r = 0; r < 4; ++r)
#pragma unroll
        for (int c = 0; c < 4; ++c) {
          tot[r][c] = __fadd_rn(tot[r][c], acc[r][c]);
          acc[r][c] = 0.0f;
        }
    }
  }

#pragma unroll
  for (int r = 0; r < 4; ++r) {
    const int m = m0 + ty * 4 + r;
#pragma unroll
    for (int c = 0; c < 4; ++c) {
      const int n = n0 + tx * 4 + c;
      float v = tot[r][c];
      if (bias) v = __fadd_rn(v, bias[n]);
      if (RELU) v = fmaxf(v, 0.0f);
      C[(long long)m * ldc + n] = v;
    }
  }
}

// ---------------------------------------------------------------------------
// Transpose K head-slices: Kt[(b*16+h)*64 + e][s] = Kf[(b*1024+s)][h*64+e].
// Tiled 64x64 via LDS; fully coalesced both sides.
// ---------------------------------------------------------------------------
__global__ __launch_bounds__(256) void transpose_k(const float* __restrict__ Kf,
                                                   float* __restrict__ Kt) {
  __shared__ float tl[64][65];
  const int bh = blockIdx.y;  // b*16+h
  const int b = bh >> 4, h = bh & 15;
  const int s0 = blockIdx.x * 64;
  const int t = threadIdx.x;
#pragma unroll
  for (int i = 0; i < 16; ++i) {
    const int idx = i * 256 + t;
    const int sr = idx >> 6, e = idx & 63;
    tl[sr][e] = Kf[(((long long)(b << 10) + s0 + sr) << 10) + (h << 6) + e];
  }
  __syncthreads();
#pragma unroll
  for (int i = 0; i < 16; ++i) {
    const int idx = i * 256 + t;
    const int er = idx >> 6, s = idx & 63;
    Kt[(((long long)(bh << 6) + er) << 10) + s0 + s] = tl[s][er];
  }
}

// ---------------------------------------------------------------------------
// Pass 1: bit-exact scores. Block = 256 threads = 4 waves = 32 rows (same
// b,h). Wave holds 8 q-vectors in registers (lane e holds q[e]); K tile
// [64][256] staged from Kt (conflict-free b128). Per e: 1 ds_read_b128 ->
// 32 FMAs (8 rows x 4 cols). Chain: ascending e, fmaf - identical rounding
// to the reference model. Raw scores -> Sraw (the A region).
// ---------------------------------------------------------------------------
__global__ __launch_bounds__(256) void score_pass1(
    const float* __restrict__ Qf, const float* __restrict__ Kt,
    float* __restrict__ Sraw) {
#pragma clang fp contract(off)
  __shared__ float Ks[64][256];

  const int t = threadIdx.x;
  const int wv = t >> 6, u = t & 63;
  const int row0 = blockIdx.x * 32;  // 32 consecutive rows, same (b,h)
  const int b = row0 >> 14, h = (row0 >> 10) & 15;
  const int l0 = row0 & 1023;
  const int bh = (b << 4) + h;

  float qreg[8];
  const int rbase = l0 + wv * 8;
#pragma unroll
  for (int r = 0; r < 8; ++r)
    qreg[r] =
        Qf[(((long long)(b << 10) + rbase + r) << 10) + (h << 6) + u];

  const float* KtBase = Kt + ((long long)(bh << 6) << 10);  // [64][1024]

  for (int wt = 0; wt < 4; ++wt) {
    __syncthreads();
#pragma unroll
    for (int i = 0; i < 16; ++i) {
      const int idx = i * 256 + t;
      const int e = idx >> 6, uu = idx & 63;
      *reinterpret_cast<float4*>(&Ks[e][4 * uu]) =
          *reinterpret_cast<const float4*>(
              &KtBase[((long long)e << 10) + wt * 256 + 4 * uu]);
    }
    __syncthreads();

    float acc[8][4];
#pragma unroll
    for (int r = 0; r < 8; ++r)
#pragma unroll
      for (int c = 0; c < 4; ++c) acc[r][c] = 0.0f;

#pragma unroll 8
    for (int e = 0; e < 64; ++e) {
      const float4 k4 = *reinterpret_cast<const float4*>(&Ks[e][4 * u]);
#pragma unroll
      for (int r = 0; r < 8; ++r) {
        const float qv = __uint_as_float(
            __builtin_amdgcn_readlane(__float_as_uint(qreg[r]), e));
        acc[r][0] = fmaf(qv, k4.x, acc[r][0]);
        acc[r][1] = fmaf(qv, k4.y, acc[r][1]);
        acc[r][2] = fmaf(qv, k4.z, acc[r][2]);
        acc[r][3] = fmaf(qv, k4.w, acc[r][3]);
      }
    }

#pragma unroll
    for (int r = 0; r < 8; ++r) {
      float4 o;
      o.x = acc[r][0];
      o.y = acc[r][1];
      o.z = acc[r][2];
      o.w = acc[r][3];
      *reinterpret_cast<float4*>(
          &Sraw[((long long)(row0 + wv * 8 + r) << 10) + wt * 256 + 4 * u]) =
          o;
    }
  }
}

// ---------------------------------------------------------------------------
// Pass 2: top-8 threshold + masked softmax, in place on raw scores (A
// region). One wave per row; coalesced global reads, no LDS. Emits compact
// (idx,w) lists for the sparse A*v step.
// ---------------------------------------------------------------------------
__global__ __launch_bounds__(512) void topk_pass2(
    float* __restrict__ A, int* __restrict__ outIdx,
    float* __restrict__ outW, int* __restrict__ outCnt) {
  const int tid = threadIdx.x;
  const int wave = tid >> 6, lane = tid & 63;
  const long long row = (long long)blockIdx.x * 8 + wave;
  float* a = A + (row << 10);

  float s[16];
#pragma unroll
  for (int j = 0; j < 16; ++j) s[j] = a[j * 64 + lane];

  // iterative top-8: find+remove max 8 times (multiplicity-correct)
  unsigned act = 0xFFFFu;
  float rowmax = 0.f, thresh = 0.f;
  for (int it = 0; it < TOPK_; ++it) {
    float lm = -INFINITY;
#pragma unroll
    for (int j = 0; j < 16; ++j)
      if (act & (1u << j)) lm = fmaxf(lm, s[j]);
    float m = lm;
#pragma unroll
    for (int d = 1; d < 64; d <<= 1) m = fmaxf(m, __shfl_xor(m, d));
    if (it == 0) rowmax = m;
    thresh = m;
    const bool has = (lm == m);
    const unsigned long long msk = __ballot(has);
    const int owner = __ffsll((long long)msk) - 1;
    if (lane == owner) {
      bool done = false;
#pragma unroll
      for (int j = 0; j < 16; ++j) {
        if (!done && (act & (1u << j)) && s[j] == m) {
          act &= ~(1u << j);
          done = true;
        }
      }
    }
  }

  float e16[16];
  float zsum = 0.f;
#pragma unroll
  for (int j = 0; j < 16; ++j) {
    const bool kept = (s[j] >= thresh);
    e16[j] = kept ? expf((s[j] - rowmax) * 0.125f) : 0.0f;
    zsum += e16[j];
  }
#pragma unroll
  for (int d = 1; d < 64; d <<= 1) zsum += __shfl_xor(zsum, d);
  const float inv = 1.0f / zsum;

  int cnt = 0;
#pragma unroll
  for (int j = 0; j < 16; ++j) {
    const bool kept = (s[j] >= thresh);
    const float w = e16[j] * inv;
    a[j * 64 + lane] = kept ? w : 0.0f;
    const unsigned long long mk = __ballot(kept);
    if (kept) {
      const int pos = cnt + __popcll(mk & ((1ull << lane) - 1ull));
      if (pos < 16) {
        outIdx[row * 16 + pos] = j * 64 + lane;
        outW[row * 16 + pos] = w;
      }
    }
    cnt += __popcll(mk);
  }
  if (lane == 0) outCnt[row] = cnt < 16 ? cnt : 16;
}

// ---------------------------------------------------------------------------
// Sparse A*v from compact lists. One wave per row (lane = e).
// ---------------------------------------------------------------------------
__global__ __launch_bounds__(256) void vagg_kernel(
    const int* __restrict__ idx, const float* __restrict__ w,
    const int* __restrict__ cnt, const float* __restrict__ Vp,
    float* __restrict__ Vagg) {
  const int wave = threadIdx.x >> 6;
  const int lane = threadIdx.x & 63;
  const long long row = (long long)blockIdx.x * 4 + wave;  // (b*16+h)*1024+l
  const int b = (int)(row >> 14);
  const int h = (int)((row >> 10) & 15);
  const int l = (int)(row & 1023);
  const int n = cnt[row];
  float acc = 0.0f;
  for (int i = 0; i < n; ++i) {
    const int sI = idx[row * 16 + i];
    const float ww = w[row * 16 + i];
    acc += ww * Vp[((long long)((b << 10) + sI) << 10) + (h << 6) + lane];
  }
  Vagg[((long long)((b << 10) + l) << 10) + (h << 6) + lane] = acc;
}

extern "C" void kernel_launch(void* const* d_in, const int* in_sizes, int n_in,
                              void* d_out, int out_size, void* d_ws,
                              size_t ws_size, hipStream_t stream) {
  const float* queries = (const float*)d_in[0];
  const float* keys = (const float*)d_in[1];
  const float* values = (const float*)d_in[2];
  const float* Wq = (const float*)d_in[3];
  const float* bq = (const float*)d_in[4];
  const float* Wk = (const float*)d_in[5];
  const float* bk = (const float*)d_in[6];
  const float* Wv = (const float*)d_in[7];
  const float* bv = (const float*)d_in[8];
  const float* Wo = (const float*)d_in[9];
  const float* bo = (const float*)d_in[10];

  float* out = (float*)d_out;                   // [B,L,D]
  float* Aout = out + (long long)B_ * L_ * D_;  // [B,H,L,S]

  char* ws = (char*)d_ws;
  const size_t MD = (size_t)B_ * L_ * D_ * sizeof(float);  // 33.55 MB
  const size_t NL = (size_t)B_ * H_ * L_;                   // 131072 rows
  float* Qf = (float*)ws;
  float* Kf = (float*)(ws + MD);
  float* Kt = (float*)(ws + 2 * MD);
  int* tIdx = (int*)(ws + 3 * MD);
  float* tW = (float*)(ws + 3 * MD + NL * 16 * 4);
  int* tCnt = (int*)(ws + 3 * MD + NL * 16 * 8);
  float* Vb = (float*)(ws + 3 * MD + NL * 16 * 8 + NL * 4);
  float* Vagg = Kt;  // Kt dead after score_pass1

  const dim3 blk(256);
  const int M = B_ * L_;  // 8192

  // Q = relu(queries @ Wq^T + bq)   [bit-exact chain]
  gemm_abt<1><<<dim3(16, M / 64), blk, 0, stream>>>(queries, Wq, bq, Qf, M, D_,
                                                    D_, D_, D_, D_);
  // K = keys @ Wk^T + bk            [bit-exact chain]
  gemm_abt<0><<<dim3(16, M / 64), blk, 0, stream>>>(keys, Wk, bk, Kf, M, D_,
                                                    D_, D_, D_, D_);
  // Kt[b,h,e,s] = Kf[b,s,h,e]
  transpose_k<<<dim3(16, B_ * H_), blk, 0, stream>>>(Kf, Kt);

  // Pass 1: bit-exact raw scores -> A region
  score_pass1<<<(int)(NL / 32), blk, 0, stream>>>(Qf, Kt, Aout);

  // V = relu(values @ Wv^T + bv)
  gemm_abt<1><<<dim3(16, M / 64), blk, 0, stream>>>(values, Wv, bv, Vb, M, D_,
                                                    D_, D_, D_, D_);

  // Pass 2: top-8 + softmax in place + compact lists
  topk_pass2<<<(int)(NL / 8), dim3(512), 0, stream>>>(Aout, tIdx, tW, tCnt);

  // Vagg[b,l,h,:] = sum_s A * v   (writes into Kt slot)
  vagg_kernel<<<(int)(NL / 4), blk, 0, stream>>>(tIdx, tW, tCnt, Vb, Vagg);

  // out = Vagg @ Wo^T + bo
  gemm_abt<0><<<dim3(16, M / 64), blk, 0, stream>>>(Vagg, Wo, bo, out, M, D_,
                                                    D_, D_, D_, D_);
}